// Round 8
// baseline (74.423 us; speedup 1.0000x reference)
//
#include <hip/hip_runtime.h>
#include <hip/hip_bf16.h>
#include <stdint.h>

#define IN_DIM  1024
#define LOW     128
#define OUT_DIM 1024
#define BATCH   8
#define SEQ     2048

typedef unsigned short u16;
typedef short bf16x8 __attribute__((ext_vector_type(8)));
typedef unsigned short u16x4 __attribute__((ext_vector_type(4)));
typedef float f32x4 __attribute__((ext_vector_type(4)));

__device__ __forceinline__ u16 f2bf(float f) {
    union { float f; uint32_t u; } v;
    v.f = f;
    uint32_t u = v.u;
    return (u16)((u + 0x7fffu + ((u >> 16) & 1u)) >> 16);
}

// ---------------------------------------------------------------------------
// gen_w v7: CONTIGUOUS block footprint (the one macro-property all fast
// streaming kernels here share). Block = 1024 CONSECUTIVE p-rows = 512KB
// contiguous read. grid 256 (1/CU), 512 threads (8 waves), no barriers in
// the stream. MFMA math identical to v6 (passed, absmax 0.0195): A-frags
// direct from global (lane lr=row, hi=k-group), B = bf16(k) in 16 VGPRs,
// C/D col=lane&15 (=batch), row=hi*4+j. 3-deep tile pipeline/wave.
//   D-blocks (bid<128):  p = d*128+l  -> tb -> DgT[b][l][d0..d0+8] 16B runs
//   U-blocks (bid>=128): p = l*1024+o -> tb -> Utmp[l][b][o] 2KB runs
// ---------------------------------------------------------------------------
__global__ __launch_bounds__(512) void gen_w(const float* __restrict__ Dm,
                                             const float* __restrict__ Um,
                                             const float* __restrict__ kv,
                                             u16* __restrict__ DgT,
                                             u16* __restrict__ Utmp) {
    __shared__ u16 tb[8 * 1032];   // [b][ploc 0..1023] (+8 pad), 16.5 KB

    int t = threadIdx.x;
    int bid = blockIdx.x;
    bool isU = bid >= 128;
    const float* src = isU ? Um : Dm;
    size_t p0 = (size_t)(isU ? bid - 128 : bid) * 1024;

    int lane = t & 63, w = t >> 6;
    int lr = lane & 15;            // A-row (tile-local p) / C-col (batch)
    int hi = lane >> 4;            // k-group / C row-group

    // B-fragments: bf16(k[batch=lr][k]), k = ks*32 + hi*8 + j; rows 8..15 = 0
    bf16x8 bfrag[4];
#pragma unroll
    for (int ks = 0; ks < 4; ++ks)
#pragma unroll
        for (int j = 0; j < 8; ++j) {
            float kvf = (lr < 8) ? kv[lr * LOW + ks * 32 + hi * 8 + j] : 0.f;
            bfrag[ks][j] = (short)f2bf(kvf);
        }

    // wave w owns rows p0 + w*128 + tau*16 + lr, tau = 0..7 (contiguous 64KB)
    const float* abase = src + (p0 + (size_t)w * 128 + lr) * 128 + hi * 8;

#define ISSUE(Lb, tau)                                                        \
    {                                                                         \
        const float* rp = abase + (size_t)(tau) * 2048;                       \
        _Pragma("unroll")                                                     \
        for (int ks = 0; ks < 4; ++ks) {                                      \
            Lb[2 * ks]     = *(const f32x4*)(rp + ks * 32);                   \
            Lb[2 * ks + 1] = *(const f32x4*)(rp + ks * 32 + 4);               \
        }                                                                     \
    }

#define COMPUTE(Lb, tau)                                                      \
    {                                                                         \
        f32x4 acc = (f32x4){0.f, 0.f, 0.f, 0.f};                              \
        _Pragma("unroll")                                                     \
        for (int ks = 0; ks < 4; ++ks) {                                      \
            f32x4 v0 = Lb[2 * ks], v1 = Lb[2 * ks + 1];                       \
            bf16x8 afr;                                                       \
            afr[0] = (short)f2bf(v0.x); afr[1] = (short)f2bf(v0.y);           \
            afr[2] = (short)f2bf(v0.z); afr[3] = (short)f2bf(v0.w);           \
            afr[4] = (short)f2bf(v1.x); afr[5] = (short)f2bf(v1.y);           \
            afr[6] = (short)f2bf(v1.z); afr[7] = (short)f2bf(v1.w);           \
            acc = __builtin_amdgcn_mfma_f32_16x16x32_bf16(afr, bfrag[ks],     \
                                                          acc, 0, 0, 0);      \
        }                                                                     \
        if (lr < 8) {                                                         \
            u16x4 o4;                                                         \
            o4[0] = f2bf(acc[0]); o4[1] = f2bf(acc[1]);                       \
            o4[2] = f2bf(acc[2]); o4[3] = f2bf(acc[3]);                       \
            *(u16x4*)(tb + lr * 1032 + w * 128 + (tau) * 16 + hi * 4) = o4;   \
        }                                                                     \
    }

    f32x4 LA[8], LB[8], LC[8];
    ISSUE(LA, 0) ISSUE(LB, 1) ISSUE(LC, 2)
    COMPUTE(LA, 0) ISSUE(LA, 3)
    COMPUTE(LB, 1) ISSUE(LB, 4)
    COMPUTE(LC, 2) ISSUE(LC, 5)
    COMPUTE(LA, 3) ISSUE(LA, 6)
    COMPUTE(LB, 4) ISSUE(LB, 7)
    COMPUTE(LC, 5)
    COMPUTE(LA, 6)
    COMPUTE(LB, 7)
#undef ISSUE
#undef COMPUTE

    __syncthreads();

    if (!isU) {
        // D flush: ploc = dd*128 + l -> DgT[b][l][d0+dd], 16B runs
        int d0 = bid * 8;
#pragma unroll
        for (int g = t; g < 1024; g += 512) {
            int b = g >> 7, l = g & 127;
            bf16x8 vv;
#pragma unroll
            for (int dd = 0; dd < 8; ++dd)
                vv[dd] = (short)tb[b * 1032 + dd * 128 + l];
            *(bf16x8*)(DgT + ((size_t)(b * 128 + l) * 1024) + d0) = vv;
        }
    } else {
        // U flush: tb[b][o] -> Utmp[(l0*8+b)][o], contiguous 2KB rows
        int l0 = bid - 128;
        int b = t >> 6, o0 = (t & 63) * 16;
        u16* urow = Utmp + ((size_t)l0 * 8 + b) * 1024;
        bf16x8 v0 = *(const bf16x8*)(tb + b * 1032 + o0);
        bf16x8 v1 = *(const bf16x8*)(tb + b * 1032 + o0 + 8);
        *(bf16x8*)(urow + o0) = v0;
        *(bf16x8*)(urow + o0 + 8) = v1;
    }
}

// ---------------------------------------------------------------------------
// transposeU: Utmp[l][b][o] -> UgT[b][o][l].  8MB L2-resident traffic.
// grid = 8 b x 16 o-tiles(64) = 128 blocks, 256 threads.
// ---------------------------------------------------------------------------
__global__ __launch_bounds__(256) void transposeU(const u16* __restrict__ Utmp,
                                                  u16* __restrict__ UgT) {
    __shared__ u16 lds[128 * 72];   // [l][o-local 64 (+8 pad)]
    int t = threadIdx.x;
    int b = blockIdx.x >> 4, o0 = (blockIdx.x & 15) * 64;

    // read: 2 threads per l-row, 64B (32 o) each
    {
        int l = t >> 1, half = t & 1;
        const u16* rp = Utmp + ((size_t)l * 8 + b) * 1024 + o0 + half * 32;
#pragma unroll
        for (int i = 0; i < 4; ++i)
            *(bf16x8*)(lds + l * 72 + half * 32 + i * 8) =
                *(const bf16x8*)(rp + i * 8);
    }
    __syncthreads();

    // write: 4 threads per o-row, each gathers 32 l and stores 64B
    {
        int o = t >> 2, q = t & 3;
        u16* wp = UgT + ((size_t)b * OUT_DIM + o0 + o) * LOW + q * 32;
#pragma unroll
        for (int i = 0; i < 4; ++i) {
            bf16x8 vv;
#pragma unroll
            for (int j = 0; j < 8; ++j)
                vv[j] = (short)lds[(q * 32 + i * 8 + j) * 72 + o];
            *(bf16x8*)(wp + i * 8) = vv;
        }
    }
}

// ---------------------------------------------------------------------------
// fc1: h[b][s][l] = relu( sum_d x[b][s][d] * D[b][d][l] )  -> bf16
// tile: M=32 (s), N=128 (all l), K-loop 1024 step 64. grid = 8*64 = 512
// ---------------------------------------------------------------------------
__global__ __launch_bounds__(256) void fc1(const float* __restrict__ x,
                                           const u16* __restrict__ DgT,
                                           u16* __restrict__ h) {
    __shared__ u16 As[32][72];
    __shared__ u16 Bs[128][72];
    int t = threadIdx.x;
    int bid = blockIdx.x;
    int b = bid >> 6, st = bid & 63;
    int s0 = st * 32;
    const float* xb = x + ((size_t)b * SEQ + s0) * IN_DIM;
    const u16* Db = DgT + (size_t)b * LOW * IN_DIM;

    int w = t >> 6, lane = t & 63;
    int wm = w >> 1, wn = w & 1;
    int lr = lane & 15, hi = lane >> 4;

    f32x4 acc[4];
#pragma unroll
    for (int nf = 0; nf < 4; ++nf) acc[nf] = (f32x4){0.f, 0.f, 0.f, 0.f};

    int ar = t >> 3, ac = t & 7;
    int brt = t >> 3, bc = t & 7;

    for (int kt = 0; kt < IN_DIM / 64; ++kt) {
        int k0 = kt * 64;
#pragma unroll
        for (int i = 0; i < 2; ++i) {
            float4 v = *(const float4*)(xb + (size_t)ar * IN_DIM + k0 + ac * 4 + i * 32);
            u16x4 o;
            o.x = f2bf(v.x); o.y = f2bf(v.y); o.z = f2bf(v.z); o.w = f2bf(v.w);
            *(u16x4*)(&As[ar][ac * 4 + i * 32]) = o;
        }
#pragma unroll
        for (int i = 0; i < 4; ++i) {
            int row = brt + 32 * i;
            bf16x8 v = *(const bf16x8*)(Db + (size_t)row * IN_DIM + k0 + bc * 8);
            *(bf16x8*)(&Bs[row][bc * 8]) = v;
        }
        __syncthreads();
#pragma unroll
        for (int ks = 0; ks < 2; ++ks) {
            int kk = ks * 32 + hi * 8;
            bf16x8 af = *(const bf16x8*)(&As[wm * 16 + lr][kk]);
#pragma unroll
            for (int nf = 0; nf < 4; ++nf) {
                bf16x8 bf = *(const bf16x8*)(&Bs[wn * 64 + nf * 16 + lr][kk]);
                acc[nf] = __builtin_amdgcn_mfma_f32_16x16x32_bf16(af, bf, acc[nf], 0, 0, 0);
            }
        }
        __syncthreads();
    }
    u16* hb = h + ((size_t)b * SEQ + s0) * LOW;
#pragma unroll
    for (int nf = 0; nf < 4; ++nf) {
        int col = wn * 64 + nf * 16 + lr;
#pragma unroll
        for (int j = 0; j < 4; ++j) {
            int rrow = wm * 16 + hi * 4 + j;
            hb[(size_t)rrow * LOW + col] = f2bf(fmaxf(acc[nf][j], 0.f));
        }
    }
}

// ---------------------------------------------------------------------------
// fc2: out[b][s][o] = sum_l h[b][s][l] * U[b][l][o]   (f32 out)
// tile: 128x128, K=128 staged once. grid = 8*16*8 = 1024
// ---------------------------------------------------------------------------
__global__ __launch_bounds__(256) void fc2(const u16* __restrict__ h,
                                           const u16* __restrict__ UgT,
                                           float* __restrict__ out) {
    __shared__ u16 As[128 * 128];
    __shared__ u16 Bs[128 * 128];
    int t = threadIdx.x;
    int bid = blockIdx.x;
    int b = bid >> 7, st = (bid >> 3) & 15, ot = bid & 7;
    int s0 = st * 128, o0 = ot * 128;
    const u16* hb = h + ((size_t)b * SEQ + s0) * LOW;
    const u16* Ub = UgT + ((size_t)b * OUT_DIM + o0) * LOW;

#pragma unroll
    for (int i = 0; i < 8; ++i) {
        int ch = i * 256 + t;
        int row = ch >> 4, c = ch & 15;
        int swc = c ^ (row & 7);
        *(bf16x8*)(As + row * 128 + swc * 8) = *(const bf16x8*)(hb + (size_t)ch * 8);
        *(bf16x8*)(Bs + row * 128 + swc * 8) = *(const bf16x8*)(Ub + (size_t)ch * 8);
    }
    __syncthreads();

    int w = t >> 6, lane = t & 63;
    int wm = w >> 1, wn = w & 1;
    int lr = lane & 15, lkc = (lane >> 4);

    f32x4 acc[4][4];
#pragma unroll
    for (int mf = 0; mf < 4; ++mf)
#pragma unroll
        for (int nf = 0; nf < 4; ++nf)
            acc[mf][nf] = (f32x4){0.f, 0.f, 0.f, 0.f};

#pragma unroll
    for (int ks = 0; ks < 4; ++ks) {
        bf16x8 af[4], bfr[4];
#pragma unroll
        for (int mf = 0; mf < 4; ++mf) {
            int row = wm * 64 + mf * 16 + lr;
            int swc = (ks * 4 + lkc) ^ (row & 7);
            af[mf] = *(const bf16x8*)(As + row * 128 + swc * 8);
        }
#pragma unroll
        for (int nf = 0; nf < 4; ++nf) {
            int row = wn * 64 + nf * 16 + lr;
            int swc = (ks * 4 + lkc) ^ (row & 7);
            bfr[nf] = *(const bf16x8*)(Bs + row * 128 + swc * 8);
        }
#pragma unroll
        for (int mf = 0; mf < 4; ++mf)
#pragma unroll
            for (int nf = 0; nf < 4; ++nf)
                acc[mf][nf] = __builtin_amdgcn_mfma_f32_16x16x32_bf16(
                    af[mf], bfr[nf], acc[mf][nf], 0, 0, 0);
    }

    float* ob = out + ((size_t)b * SEQ + s0) * OUT_DIM + o0;
#pragma unroll
    for (int mf = 0; mf < 4; ++mf)
#pragma unroll
        for (int nf = 0; nf < 4; ++nf) {
            int col = wn * 64 + nf * 16 + lr;
#pragma unroll
            for (int j = 0; j < 4; ++j) {
                int rrow = wm * 64 + mf * 16 + (lane >> 4) * 4 + j;
                ob[(size_t)rrow * OUT_DIM + col] = acc[mf][nf][j];
            }
        }
}

extern "C" void kernel_launch(void* const* d_in, const int* in_sizes, int n_in,
                              void* d_out, int out_size, void* d_ws, size_t ws_size,
                              hipStream_t stream) {
    const float* x  = (const float*)d_in[0];
    const float* kv = (const float*)d_in[1];
    const float* Dm = (const float*)d_in[2];
    const float* Um = (const float*)d_in[3];
    float* out = (float*)d_out;

    u16* DgT  = (u16*)d_ws;                                   // 2 MB
    u16* UgT  = DgT + (size_t)BATCH * LOW * IN_DIM;           // 2 MB
    u16* hbuf = UgT + (size_t)BATCH * OUT_DIM * LOW;          // 4 MB
    u16* Utmp = hbuf + (size_t)BATCH * SEQ * LOW;             // 2 MB

    gen_w<<<dim3(256), dim3(512), 0, stream>>>(Dm, Um, kv, DgT, Utmp);
    transposeU<<<dim3(128), dim3(256), 0, stream>>>(Utmp, UgT);
    fc1<<<dim3(512), dim3(256), 0, stream>>>(x, DgT, hbuf);
    fc2<<<dim3(1024), dim3(256), 0, stream>>>(hbuf, UgT, out);
}

// Round 9
// 71.540 us; speedup vs baseline: 1.0403x; 1.0403x over previous
//
#include <hip/hip_runtime.h>
#include <hip/hip_bf16.h>
#include <stdint.h>

#define IN_DIM  1024
#define LOW     128
#define OUT_DIM 1024
#define BATCH   8
#define SEQ     2048

typedef unsigned short u16;
typedef short bf16x8 __attribute__((ext_vector_type(8)));
typedef unsigned short u16x4 __attribute__((ext_vector_type(4)));
typedef float f32x4 __attribute__((ext_vector_type(4)));

__device__ __forceinline__ u16 f2bf(float f) {
    union { float f; uint32_t u; } v;
    v.f = f;
    uint32_t u = v.u;
    return (u16)((u + 0x7fffu + ((u >> 16) & 1u)) >> 16);
}

// ---------------------------------------------------------------------------
// gen_half v8: v6's verified MFMA-from-global math, with the load pipeline
// FORCED to stay 4-deep in registers (launch_bounds(256,1): ~170 VGPR OK;
// v6/v7's VGPR=52/64 proved the compiler sank the loads -> latency-bound),
// and nontemporal loads (once-read stream; no L1 retention).
//   D launch: out[b][l][d] runs, NTOT=128,  MTOT=1024, sh=4
//   U launch: out[b][o][l] runs, NTOT=1024, MTOT=128,  sh=7
// Block = 256 p-rows (32 m x 8 n), 4 waves; wave w owns 4 tiles of 16 rows.
// All 32 loads (32KB/wave) issued in one burst, then 4 MFMA tiles consume.
// C/D layout col=lane&15(=batch), row=hi*4+j (verified R5/R7, absmax .0195).
// grid 512 per half (2 blocks/CU).
// ---------------------------------------------------------------------------
__global__ __launch_bounds__(256, 1) void gen_half(const float* __restrict__ src,
                                                   const float* __restrict__ kv,
                                                   u16* __restrict__ outp,
                                                   int NTOT, int MTOT, int sh) {
    __shared__ u16 tb[8 * 8 * 32];   // [b][n-local 8][m-local 32], 4 KB

    int t = threadIdx.x;
    int rb = blockIdx.x;
    int m0 = (rb >> sh) * 32;
    int n0 = (rb & ((1 << sh) - 1)) * 8;

    int lane = t & 63, w = t >> 6;
    int lr = lane & 15;            // A-row / C-col (batch) index
    int hi = lane >> 4;            // k-group / C row-group

    // B-fragments: bf16(k[batch=lr][k]), k = ks*32 + hi*8 + j; rows 8..15 = 0
    bf16x8 bfrag[4];
#pragma unroll
    for (int ks = 0; ks < 4; ++ks)
#pragma unroll
        for (int j = 0; j < 8; ++j) {
            float kvf = (lr < 8) ? kv[lr * LOW + ks * 32 + hi * 8 + j] : 0.f;
            bfrag[ks][j] = (short)f2bf(kvf);
        }

    // lane's p-row for tile tau: m = m0 + w*8 + tau*2 + (lr>>3), n = n0+(lr&7)
    const float* abase = src +
        ((size_t)(m0 + w * 8 + (lr >> 3)) * NTOT + n0 + (lr & 7)) * 128 + hi * 8;
    size_t tstep = (size_t)2 * NTOT * 128;   // floats per tau step

    // ---- burst-issue ALL 32 loads (4 tiles x 8), nontemporal, static idx
    f32x4 L[4][8];
#pragma unroll
    for (int tau = 0; tau < 4; ++tau) {
        const float* rp = abase + (size_t)tau * tstep;
#pragma unroll
        for (int ks = 0; ks < 4; ++ks) {
            L[tau][2 * ks] =
                __builtin_nontemporal_load((const f32x4*)(rp + ks * 32));
            L[tau][2 * ks + 1] =
                __builtin_nontemporal_load((const f32x4*)(rp + ks * 32 + 4));
        }
    }

    // ---- consume: 4 MFMA tiles
#pragma unroll
    for (int tau = 0; tau < 4; ++tau) {
        f32x4 acc = (f32x4){0.f, 0.f, 0.f, 0.f};
#pragma unroll
        for (int ks = 0; ks < 4; ++ks) {
            f32x4 v0 = L[tau][2 * ks], v1 = L[tau][2 * ks + 1];
            bf16x8 afr;
            afr[0] = (short)f2bf(v0.x); afr[1] = (short)f2bf(v0.y);
            afr[2] = (short)f2bf(v0.z); afr[3] = (short)f2bf(v0.w);
            afr[4] = (short)f2bf(v1.x); afr[5] = (short)f2bf(v1.y);
            afr[6] = (short)f2bf(v1.z); afr[7] = (short)f2bf(v1.w);
            acc = __builtin_amdgcn_mfma_f32_16x16x32_bf16(afr, bfrag[ks],
                                                          acc, 0, 0, 0);
        }
        if (lr < 8) {
#pragma unroll
            for (int j = 0; j < 4; ++j) {
                int r = hi * 4 + j;                  // tile row 0..15
                int mm = w * 8 + tau * 2 + (r >> 3); // block-local m 0..31
                tb[lr * 256 + (r & 7) * 32 + mm] = f2bf(acc[j]);
            }
        }
    }

    __syncthreads();   // tb visible

    // coalesced flush: 64 chunks (b,n') x 64B (32 m)  [verified R5/R7]
    int c64 = t >> 2, q4 = t & 3;
    int bw = c64 >> 3, np = c64 & 7;
    bf16x8 v = *(const bf16x8*)(tb + bw * 256 + np * 32 + q4 * 8);
    *(bf16x8*)(outp + ((size_t)(bw * NTOT + n0 + np)) * MTOT + m0 + q4 * 8) = v;
}

// ---------------------------------------------------------------------------
// fc1: h[b][s][l] = relu( sum_d x[b][s][d] * D[b][d][l] )  -> bf16
// tile: M=32 (s), N=128 (all l), K-loop 1024 step 64. grid = 8*64 = 512
// ---------------------------------------------------------------------------
__global__ __launch_bounds__(256) void fc1(const float* __restrict__ x,
                                           const u16* __restrict__ DgT,
                                           u16* __restrict__ h) {
    __shared__ u16 As[32][72];
    __shared__ u16 Bs[128][72];
    int t = threadIdx.x;
    int bid = blockIdx.x;
    int b = bid >> 6, st = bid & 63;
    int s0 = st * 32;
    const float* xb = x + ((size_t)b * SEQ + s0) * IN_DIM;
    const u16* Db = DgT + (size_t)b * LOW * IN_DIM;

    int w = t >> 6, lane = t & 63;
    int wm = w >> 1, wn = w & 1;
    int lr = lane & 15, hi = lane >> 4;

    f32x4 acc[4];
#pragma unroll
    for (int nf = 0; nf < 4; ++nf) acc[nf] = (f32x4){0.f, 0.f, 0.f, 0.f};

    int ar = t >> 3, ac = t & 7;
    int brt = t >> 3, bc = t & 7;

    for (int kt = 0; kt < IN_DIM / 64; ++kt) {
        int k0 = kt * 64;
#pragma unroll
        for (int i = 0; i < 2; ++i) {
            float4 v = *(const float4*)(xb + (size_t)ar * IN_DIM + k0 + ac * 4 + i * 32);
            u16x4 o;
            o.x = f2bf(v.x); o.y = f2bf(v.y); o.z = f2bf(v.z); o.w = f2bf(v.w);
            *(u16x4*)(&As[ar][ac * 4 + i * 32]) = o;
        }
#pragma unroll
        for (int i = 0; i < 4; ++i) {
            int row = brt + 32 * i;
            bf16x8 v = *(const bf16x8*)(Db + (size_t)row * IN_DIM + k0 + bc * 8);
            *(bf16x8*)(&Bs[row][bc * 8]) = v;
        }
        __syncthreads();
#pragma unroll
        for (int ks = 0; ks < 2; ++ks) {
            int kk = ks * 32 + hi * 8;
            bf16x8 af = *(const bf16x8*)(&As[wm * 16 + lr][kk]);
#pragma unroll
            for (int nf = 0; nf < 4; ++nf) {
                bf16x8 bf = *(const bf16x8*)(&Bs[wn * 64 + nf * 16 + lr][kk]);
                acc[nf] = __builtin_amdgcn_mfma_f32_16x16x32_bf16(af, bf, acc[nf], 0, 0, 0);
            }
        }
        __syncthreads();
    }
    u16* hb = h + ((size_t)b * SEQ + s0) * LOW;
#pragma unroll
    for (int nf = 0; nf < 4; ++nf) {
        int col = wn * 64 + nf * 16 + lr;
#pragma unroll
        for (int j = 0; j < 4; ++j) {
            int rrow = wm * 16 + hi * 4 + j;
            hb[(size_t)rrow * LOW + col] = f2bf(fmaxf(acc[nf][j], 0.f));
        }
    }
}

// ---------------------------------------------------------------------------
// fc2: out[b][s][o] = sum_l h[b][s][l] * U[b][l][o]   (f32 out)
// tile: 128x128, K=128 staged once. grid = 8*16*8 = 1024
// ---------------------------------------------------------------------------
__global__ __launch_bounds__(256) void fc2(const u16* __restrict__ h,
                                           const u16* __restrict__ UgT,
                                           float* __restrict__ out) {
    __shared__ u16 As[128 * 128];
    __shared__ u16 Bs[128 * 128];
    int t = threadIdx.x;
    int bid = blockIdx.x;
    int b = bid >> 7, st = (bid >> 3) & 15, ot = bid & 7;
    int s0 = st * 128, o0 = ot * 128;
    const u16* hb = h + ((size_t)b * SEQ + s0) * LOW;
    const u16* Ub = UgT + ((size_t)b * OUT_DIM + o0) * LOW;

#pragma unroll
    for (int i = 0; i < 8; ++i) {
        int ch = i * 256 + t;
        int row = ch >> 4, c = ch & 15;
        int swc = c ^ (row & 7);
        *(bf16x8*)(As + row * 128 + swc * 8) = *(const bf16x8*)(hb + (size_t)ch * 8);
        *(bf16x8*)(Bs + row * 128 + swc * 8) = *(const bf16x8*)(Ub + (size_t)ch * 8);
    }
    __syncthreads();

    int w = t >> 6, lane = t & 63;
    int wm = w >> 1, wn = w & 1;
    int lr = lane & 15, lkc = (lane >> 4);

    f32x4 acc[4][4];
#pragma unroll
    for (int mf = 0; mf < 4; ++mf)
#pragma unroll
        for (int nf = 0; nf < 4; ++nf)
            acc[mf][nf] = (f32x4){0.f, 0.f, 0.f, 0.f};

#pragma unroll
    for (int ks = 0; ks < 4; ++ks) {
        bf16x8 af[4], bfr[4];
#pragma unroll
        for (int mf = 0; mf < 4; ++mf) {
            int row = wm * 64 + mf * 16 + lr;
            int swc = (ks * 4 + lkc) ^ (row & 7);
            af[mf] = *(const bf16x8*)(As + row * 128 + swc * 8);
        }
#pragma unroll
        for (int nf = 0; nf < 4; ++nf) {
            int row = wn * 64 + nf * 16 + lr;
            int swc = (ks * 4 + lkc) ^ (row & 7);
            bfr[nf] = *(const bf16x8*)(Bs + row * 128 + swc * 8);
        }
#pragma unroll
        for (int mf = 0; mf < 4; ++mf)
#pragma unroll
            for (int nf = 0; nf < 4; ++nf)
                acc[mf][nf] = __builtin_amdgcn_mfma_f32_16x16x32_bf16(
                    af[mf], bfr[nf], acc[mf][nf], 0, 0, 0);
    }

    float* ob = out + ((size_t)b * SEQ + s0) * OUT_DIM + o0;
#pragma unroll
    for (int mf = 0; mf < 4; ++mf)
#pragma unroll
        for (int nf = 0; nf < 4; ++nf) {
            int col = wn * 64 + nf * 16 + lr;
#pragma unroll
            for (int j = 0; j < 4; ++j) {
                int rrow = wm * 64 + mf * 16 + (lane >> 4) * 4 + j;
                ob[(size_t)rrow * OUT_DIM + col] = acc[mf][nf][j];
            }
        }
}

extern "C" void kernel_launch(void* const* d_in, const int* in_sizes, int n_in,
                              void* d_out, int out_size, void* d_ws, size_t ws_size,
                              hipStream_t stream) {
    const float* x  = (const float*)d_in[0];
    const float* kv = (const float*)d_in[1];
    const float* Dm = (const float*)d_in[2];
    const float* Um = (const float*)d_in[3];
    float* out = (float*)d_out;

    u16* DgT  = (u16*)d_ws;                                   // 2 MB
    u16* UgT  = DgT + (size_t)BATCH * LOW * IN_DIM;           // 2 MB
    u16* hbuf = UgT + (size_t)BATCH * OUT_DIM * LOW;          // 4 MB

    gen_half<<<dim3(512), dim3(256), 0, stream>>>(Dm, kv, DgT, 128, 1024, 4);
    gen_half<<<dim3(512), dim3(256), 0, stream>>>(Um, kv, UgT, 1024, 128, 7);
    fc1<<<dim3(512), dim3(256), 0, stream>>>(x, DgT, hbuf);
    fc2<<<dim3(1024), dim3(256), 0, stream>>>(hbuf, UgT, out);
}